// Round 5
// baseline (6115.166 us; speedup 1.0000x reference)
//
#include <hip/hip_runtime.h>
#include <cstdint>

// AttentionDecoder: B=128, L=196, T_dec=31, E=H=F=A=512, V=10000
// Out: logits (128*31*10000) | alphas (128*31*196) | dec_len (128), fp32.

#define DEV __device__ __forceinline__

typedef __bf16 bf16x8 __attribute__((ext_vector_type(8)));
typedef float  f32x4  __attribute__((ext_vector_type(4)));
typedef unsigned short us8 __attribute__((ext_vector_type(8)));

DEV float sigmf(float v) { return 1.f / (1.f + expf(-v)); }

DEV ushort f2bf(float f) {
  union { float f; uint32_t u; } c; c.f = f;
  uint32_t u = c.u;
  return (ushort)((u + 0x7FFFu + ((u >> 16) & 1u)) >> 16);
}
DEV float bf2f(ushort h) {
  union { uint32_t u; float f; } c; c.u = ((uint32_t)h) << 16;
  return c.f;
}
DEV void cvt8(const float* __restrict__ s, ushort* __restrict__ d) {
  float4 a = *(const float4*)s;
  float4 b = *(const float4*)(s + 4);
  ushort4 lo = make_ushort4(f2bf(a.x), f2bf(a.y), f2bf(a.z), f2bf(a.w));
  ushort4 hi = make_ushort4(f2bf(b.x), f2bf(b.y), f2bf(b.z), f2bf(b.w));
  *(ushort4*)d = lo;
  *(ushort4*)(d + 4) = hi;
}

// Software grid barrier (agent scope: arrive is ACQ_REL on cnt, last arriver
// RELEASE-stores gen, waiters ACQUIRE-load gen — transitive happens-before
// publishes every block's prior writes across XCDs; same mechanism as
// grid.sync but launched plainly: graph-capture-safe).
// bar[0]=count, bar[64]=generation (separate cachelines). Sense-reversing:
// safe across overlapping generations and graph replays (monotonic gen).
DEV void gbar(unsigned* bar, unsigned nblk) {
  __syncthreads();
  if (threadIdx.x == 0) {
    unsigned* cnt = bar;
    unsigned* gen = bar + 64;
    unsigned g = __hip_atomic_load(gen, __ATOMIC_RELAXED, __HIP_MEMORY_SCOPE_AGENT);
    unsigned a = __hip_atomic_fetch_add(cnt, 1u, __ATOMIC_ACQ_REL,
                                        __HIP_MEMORY_SCOPE_AGENT);
    if (a == nblk - 1u) {
      __hip_atomic_store(cnt, 0u, __ATOMIC_RELAXED, __HIP_MEMORY_SCOPE_AGENT);
      __hip_atomic_store(gen, g + 1u, __ATOMIC_RELEASE, __HIP_MEMORY_SCOPE_AGENT);
    } else {
      while (__hip_atomic_load(gen, __ATOMIC_ACQUIRE,
                               __HIP_MEMORY_SCOPE_AGENT) == g)
        __builtin_amdgcn_s_sleep(2);
    }
  }
  __syncthreads();
}

// ---------------------------------------------------------------------------
// 128x128-tile bf16 MFMA GEMM: C = A(128xK) @ W(NxK)^T tile. 256 thr = 4 waves.
// mode 0: fp32 out (+bias if non-null); 1: bf16 out;
// mode 3: logits remap row=t*128+b -> Cf[b][t][col], mask t<declen[b], col<Ncols.
DEV void mfma_body(ushort* As, ushort* Ws, int mt, int nt,
                   const ushort* __restrict__ A, int lda,
                   const ushort* __restrict__ W, int ldw,
                   int K, int mode, const float* __restrict__ bias,
                   float* __restrict__ Cf, ushort* __restrict__ Cb, int ldc,
                   int Ncols, const int* __restrict__ declen)
{
  const int tid = threadIdx.x;
  const int m0 = mt * 128, n0 = nt * 128;
  const int wv = tid >> 6, lane = tid & 63;
  const int rw = (wv & 1) * 64, cw = (wv >> 1) * 64;
  const int lrow = lane & 15, lk = (lane >> 4) * 8;
  f32x4 acc[4][4];
#pragma unroll
  for (int i = 0; i < 4; ++i)
#pragma unroll
    for (int j = 0; j < 4; ++j) acc[i][j] = (f32x4){0.f, 0.f, 0.f, 0.f};

  const int srow = tid >> 3;
  const int sc8  = tid & 7;
  for (int k0 = 0; k0 < K; k0 += 64) {
    __syncthreads();
#pragma unroll
    for (int it = 0; it < 4; ++it) {
      int row = it * 32 + srow;
      *(uint4*)&As[row * 72 + sc8 * 8] =
          *(const uint4*)&A[(size_t)(m0 + row) * lda + k0 + sc8 * 8];
      *(uint4*)&Ws[row * 72 + sc8 * 8] =
          *(const uint4*)&W[(size_t)(n0 + row) * ldw + k0 + sc8 * 8];
    }
    __syncthreads();
#pragma unroll
    for (int ks = 0; ks < 64; ks += 32) {
      bf16x8 af[4], bfr[4];
#pragma unroll
      for (int i = 0; i < 4; ++i)
        af[i] = *(const bf16x8*)&As[(rw + i * 16 + lrow) * 72 + ks + lk];
#pragma unroll
      for (int j = 0; j < 4; ++j)
        bfr[j] = *(const bf16x8*)&Ws[(cw + j * 16 + lrow) * 72 + ks + lk];
#pragma unroll
      for (int i = 0; i < 4; ++i)
#pragma unroll
        for (int j = 0; j < 4; ++j)
          acc[i][j] = __builtin_amdgcn_mfma_f32_16x16x32_bf16(af[i], bfr[j],
                                                              acc[i][j], 0, 0, 0);
    }
  }
  const int rsub = (lane >> 4) * 4;
#pragma unroll
  for (int i = 0; i < 4; ++i) {
#pragma unroll
    for (int j = 0; j < 4; ++j) {
      int col = n0 + cw + j * 16 + lrow;
#pragma unroll
      for (int r = 0; r < 4; ++r) {
        int row = m0 + rw + i * 16 + rsub + r;
        float v = acc[i][j][r];
        if (mode == 0) {
          Cf[(size_t)row * ldc + col] = bias ? v + bias[col] : v;
        } else if (mode == 1) {
          Cb[(size_t)row * ldc + col] = f2bf(v);
        } else {
          int tt = row >> 7, bb = row & 127;
          if (col < Ncols) {
            float o = (tt < declen[bb]) ? v + bias[col] : 0.f;
            Cf[((size_t)bb * 31 + tt) * 10000 + col] = o;
          }
        }
      }
    }
  }
}

// generic (used for annp)
__global__ __launch_bounds__(256) void k_mfma(
    const ushort* __restrict__ A, int lda, const ushort* __restrict__ W, int ldw,
    int K, int mode, const float* __restrict__ bias,
    float* __restrict__ Cf, ushort* __restrict__ Cb, int ldc, int Ncols,
    const int* __restrict__ declen)
{
  __shared__ ushort As[128 * 72];
  __shared__ ushort Ws[128 * 72];
  mfma_body(As, Ws, blockIdx.y, blockIdx.x, A, lda, W, ldw, K, mode, bias,
            Cf, Cb, ldc, Ncols, declen);
}

// Logits with XCD swizzle: same col-tile stays on one XCD across row-tiles.
__global__ __launch_bounds__(256) void k_logits(
    const ushort* __restrict__ preA, const ushort* __restrict__ Wo,
    const float* __restrict__ b_out, float* __restrict__ out_logits,
    const int* __restrict__ declen)
{
  __shared__ ushort As[128 * 72];
  __shared__ ushort Ws[128 * 72];
  int id = blockIdx.x;
  int x = id & 7, g = id >> 3;
  int G = g / 31, row = g - G * 31;
  int col = G * 8 + x;
  if (col >= 79) return;
  mfma_body(As, Ws, row, col, preA, 512, Wo, 512, 512, 3, b_out,
            out_logits, nullptr, 10000, 10000, declen);
}

// ---------------------------------------------------------------------------
// Per-step task bodies.

// gates: 128 tasks = 16 N-tiles x 8 K-splits (K=192 each). fp32 partials.
// x_cur row = [emb(t) | gctx(t) | h(t-1)], Wg is gate-interleaved [W_ih|W_hh].
DEV void gates_task(int task, ushort* As, ushort* Ws,
                    const ushort* __restrict__ x_cur,
                    const ushort* __restrict__ Wg, float* __restrict__ gP)
{
  int nt = task & 15, ks = task >> 4;
  mfma_body(As, Ws, 0, nt, x_cur + ks * 192, 1536, Wg + ks * 192, 1536, 192, 0,
            nullptr, gP + (size_t)ks * 262144, nullptr, 2048, 2048, nullptr);
}

// tailhg: 32 tasks = 8 N-tiles x 4 K-splits (K=128). h(t) @ Whg^T where
// Whg = [W_att_h ; W_beta] stacked (1024x512). Partials hgP[ks][128][1024].
DEV void tailhg_task(int task, ushort* As, ushort* Ws,
                     const ushort* __restrict__ x_cur,
                     const ushort* __restrict__ Whg, float* __restrict__ hgP)
{
  int nt = task & 7, ks = task >> 3;
  mfma_body(As, Ws, 0, nt, x_cur + 1024 + ks * 128, 1536, Whg + ks * 128, 512,
            128, 0, nullptr, hgP + (size_t)ks * 131072, nullptr, 1024, 1024,
            nullptr);
}

// pre: 32 tasks = 4 N-tiles x 8 K-splits (K=192). After lstm, x_cur holds
// exactly [emb(t)|gctx(t)|h(t)], so pre reads x_cur directly (no x_all copy).
// Wcat2 = [W_y|W_z|W_h] (512x1536). Runs on idle blocks during tail phase.
// (Inactive b: h is frozen h_out, so pre differs from reference there — but
//  those logits rows are masked to 0 in mode 3, matching the reference.)
DEV void pre_task(int j, ushort* As, ushort* Ws,
                  const ushort* __restrict__ x_cur,
                  const ushort* __restrict__ Wcat2, float* __restrict__ preP)
{
  int nt = j & 3, ks = j >> 2;
  mfma_body(As, Ws, 0, nt, x_cur + ks * 192, 1536, Wcat2 + ks * 192, 1536, 192,
            0, nullptr, preP + (size_t)ks * 65536, nullptr, 512, 512, nullptr);
}

// LSTM pointwise: sums 8 gate partials (gate-interleaved float4) + bias.
DEV void lstm_task(int idx, int t, const float* __restrict__ gP,
                   const float* __restrict__ biascR, float* __restrict__ c,
                   ushort* __restrict__ x_cur, const int* __restrict__ declen)
{
  int b = idx >> 9, f = idx & 511;
  if (t >= declen[b]) return;
  float4 v = make_float4(0.f, 0.f, 0.f, 0.f);
#pragma unroll
  for (int ks = 0; ks < 8; ++ks) {
    float4 pv = *(const float4*)&gP[(size_t)ks * 262144 + b * 2048 + f * 4];
    v.x += pv.x; v.y += pv.y; v.z += pv.z; v.w += pv.w;
  }
  float4 bc = *(const float4*)&biascR[f * 4];
  float i_ = v.x + bc.x, f_ = v.y + bc.y, g_ = v.z + bc.z, o_ = v.w + bc.w;
  float cn = sigmf(f_) * c[idx] + sigmf(i_) * tanhf(g_);
  float hn = sigmf(o_) * tanhf(cn);
  c[idx] = cn;
  x_cur[b * 1536 + 1024 + f] = f2bf(hn);
}

// Attention step for one batch element, 256 threads (4 waves).
// Sums hp/gp partials (+biases), combines pre partials for step t-1,
// computes scores/softmax/context, writes emb+gctx into x_cur.
DEV void attn_task(int b, int t,
    const ushort* __restrict__ annp_bf, const ushort* __restrict__ ann_bf,
    const float* __restrict__ hgP, const float* __restrict__ preP,
    const float* __restrict__ b_hf, const float* __restrict__ b_beta,
    const float* __restrict__ wv, const float* __restrict__ bv,
    const int* __restrict__ captions, const float* __restrict__ E_emb,
    const int* __restrict__ declen, ushort* __restrict__ x_cur,
    ushort* __restrict__ preA_bf, float* __restrict__ out_alpha,
    float* s_hp, float* s_sc, float* s_red)
{
  const int tid = threadIdx.x, lane = tid & 63, wvx = tid >> 6;
  for (int f = tid; f < 512; f += 256) {
    int o = b * 1024 + f;
    s_hp[f] = b_hf[f] + hgP[o] + hgP[131072 + o] + hgP[262144 + o]
            + hgP[393216 + o];
    if (t > 0) {
      int o2 = b * 512 + f;
      float s = 0.f;
#pragma unroll
      for (int ks = 0; ks < 8; ++ks) s += preP[ks * 65536 + o2];
      preA_bf[((size_t)(t - 1) * 128 + b) * 512 + f] = f2bf(tanhf(s));
    }
  }
  __syncthreads();
  // scores: each wave owns rows {wvx*4 + 16k + i, i<4}; 4 rows in flight so the
  // 4 shuffle-reduce chains pipeline.
  const ushort* ap = annp_bf + (size_t)b * 196 * 512;
  float hv[8], wt[8];
#pragma unroll
  for (int j = 0; j < 8; ++j) {
    hv[j] = s_hp[lane * 8 + j];
    wt[j] = wv[lane * 8 + j];
  }
  float bvv = bv[0];
  for (int l0 = wvx * 4; l0 < 196; l0 += 16) {
    const ushort* r = ap + (size_t)l0 * 512 + lane * 8;
    us8 v0 = *(const us8*)(r);
    us8 v1 = *(const us8*)(r + 512);
    us8 v2 = *(const us8*)(r + 1024);
    us8 v3 = *(const us8*)(r + 1536);
    float a0 = 0.f, a1 = 0.f, a2 = 0.f, a3 = 0.f;
#pragma unroll
    for (int j = 0; j < 8; ++j) {
      a0 = fmaf(fmaxf(bf2f(v0[j]) + hv[j], 0.f), wt[j], a0);
      a1 = fmaf(fmaxf(bf2f(v1[j]) + hv[j], 0.f), wt[j], a1);
      a2 = fmaf(fmaxf(bf2f(v2[j]) + hv[j], 0.f), wt[j], a2);
      a3 = fmaf(fmaxf(bf2f(v3[j]) + hv[j], 0.f), wt[j], a3);
    }
#pragma unroll
    for (int off = 32; off; off >>= 1) {
      a0 += __shfl_xor(a0, off, 64);
      a1 += __shfl_xor(a1, off, 64);
      a2 += __shfl_xor(a2, off, 64);
      a3 += __shfl_xor(a3, off, 64);
    }
    if (lane == 0) {
      s_sc[l0]     = a0 + bvv;
      s_sc[l0 + 1] = a1 + bvv;
      s_sc[l0 + 2] = a2 + bvv;
      s_sc[l0 + 3] = a3 + bvv;
    }
  }
  __syncthreads();
  float v = (tid < 196) ? s_sc[tid] : -3.402823466e38f;
  float m = v;
#pragma unroll
  for (int off = 32; off; off >>= 1) m = fmaxf(m, __shfl_xor(m, off, 64));
  if (lane == 0) s_red[wvx] = m;
  __syncthreads();
  m = fmaxf(fmaxf(s_red[0], s_red[1]), fmaxf(s_red[2], s_red[3]));
  float e = (tid < 196) ? expf(v - m) : 0.f;
  float s = e;
#pragma unroll
  for (int off = 32; off; off >>= 1) s += __shfl_xor(s, off, 64);
  if (lane == 0) s_red[4 + wvx] = s;
  __syncthreads();
  s = (s_red[4] + s_red[5]) + (s_red[6] + s_red[7]);
  float inv = 1.f / s;
  bool active = t < declen[b];
  if (tid < 196) {
    float al = e * inv;
    s_sc[tid] = al;
    out_alpha[((size_t)b * 31 + t) * 196 + tid] = active ? al : 0.f;
  }
  __syncthreads();
  // context (4 independent accumulator chains; 196 = 49*4) + gate + emb write
  const ushort* ab = ann_bf + (size_t)b * 196 * 512;
  int tok = captions[b * 32 + t];
  for (int f = tid; f < 512; f += 256) {
    const ushort* col = ab + f;
    float c0 = 0.f, c1 = 0.f, c2 = 0.f, c3 = 0.f;
#pragma unroll 7
    for (int l = 0; l < 196; l += 4) {
      c0 = fmaf(s_sc[l],     bf2f(col[(size_t)l * 512]),        c0);
      c1 = fmaf(s_sc[l + 1], bf2f(col[(size_t)(l + 1) * 512]),  c1);
      c2 = fmaf(s_sc[l + 2], bf2f(col[(size_t)(l + 2) * 512]),  c2);
      c3 = fmaf(s_sc[l + 3], bf2f(col[(size_t)(l + 3) * 512]),  c3);
    }
    float ctx = (c0 + c1) + (c2 + c3);
    int o2 = b * 1024 + 512 + f;
    float g = sigmf(hgP[o2] + hgP[131072 + o2] + hgP[262144 + o2]
                    + hgP[393216 + o2] + b_beta[f]);
    x_cur[b * 1536 + 512 + f] = f2bf(g * ctx);
    x_cur[b * 1536 + f] = f2bf(E_emb[(size_t)tok * 512 + f]);
  }
}

// ---------------------------------------------------------------------------
// Persistent step loop: 128 blocks x 256 threads, all 31 steps, software grid
// barrier (plain launch — no cooperative API, graph-capture-safe).
// Phases per step:
//   attn (128 blk, also combines pre[t-1]) | gates (128 blk) | lstm (all) |
//   tail: tailhg (blk 0-31, skipped at t=30) + pre[t] (blk 32-63, free — runs
//   on otherwise-idle CUs, reads x_cur). Epilogue combines pre[30].
__global__ __launch_bounds__(256) void k_steps(
    const ushort* __restrict__ annp_bf, const ushort* __restrict__ ann_bf,
    float* __restrict__ hgP, float* __restrict__ preP,
    const float* __restrict__ b_hf, const float* __restrict__ b_beta,
    const float* __restrict__ wv, const float* __restrict__ bv,
    const int* __restrict__ captions, const float* __restrict__ E_emb,
    const int* __restrict__ declen, ushort* __restrict__ x_cur,
    ushort* __restrict__ preA_bf, float* __restrict__ out_alpha,
    const ushort* __restrict__ Wg, float* __restrict__ gP,
    const float* __restrict__ biascR, float* __restrict__ cbuf,
    const ushort* __restrict__ Whg, const ushort* __restrict__ Wcat2,
    unsigned* bar)
{
  __shared__ ushort As[128 * 72];
  __shared__ ushort Ws[128 * 72];
  __shared__ float s_hp[512];
  __shared__ float s_sc[200];
  __shared__ float s_red[8];
  const int bid = blockIdx.x;
  for (int t = 0; t < 31; ++t) {
    attn_task(bid, t, annp_bf, ann_bf, hgP, preP, b_hf, b_beta, wv, bv,
              captions, E_emb, declen, x_cur, preA_bf, out_alpha,
              s_hp, s_sc, s_red);
    gbar(bar, 128);
    gates_task(bid, As, Ws, x_cur, Wg, gP);
    gbar(bar, 128);
    lstm_task(bid * 512 + threadIdx.x, t, gP, biascR, cbuf, x_cur, declen);
    lstm_task(bid * 512 + 256 + threadIdx.x, t, gP, biascR, cbuf, x_cur, declen);
    gbar(bar, 128);
    if (bid < 32) {
      if (t < 30) tailhg_task(bid, As, Ws, x_cur, Whg, hgP);
    } else if (bid < 64) {
      pre_task(bid - 32, As, Ws, x_cur, Wcat2, preP);
    }
    gbar(bar, 128);
  }
  // epilogue: combine pre partials for t=30 (block bid handles b=bid).
  for (int f = threadIdx.x; f < 512; f += 256) {
    int o = bid * 512 + f;
    float s = 0.f;
#pragma unroll
    for (int ks = 0; ks < 8; ++ks) s += preP[ks * 65536 + o];
    preA_bf[((size_t)30 * 128 + bid) * 512 + f] = f2bf(tanhf(s));
  }
}

// tailhg standalone: init hp/gp pass from h0.
__global__ __launch_bounds__(256) void k_tailhg(
    const ushort* __restrict__ x_cur, const ushort* __restrict__ Whg,
    float* __restrict__ hgP)
{
  __shared__ ushort As[128 * 72];
  __shared__ ushort Ws[128 * 72];
  tailhg_task(blockIdx.x, As, Ws, x_cur, Whg, hgP);
}

// ---------------------------------------------------------------------------
// Prep: weight conversions. Wg is gate-interleaved: row f*4+g <- orig row
// g*512+f of [W_ih|W_hh]; biascR likewise. Whg = [W_att_h ; W_beta].
__global__ __launch_bounds__(256) void k_prep(
    const float* __restrict__ W_ih, const float* __restrict__ W_hh,
    const float* __restrict__ b_ih, const float* __restrict__ b_hh,
    const float* __restrict__ W_y, const float* __restrict__ W_h,
    const float* __restrict__ W_z, const float* __restrict__ W_out,
    const float* __restrict__ W_att_f, const float* __restrict__ W_att_h,
    const float* __restrict__ W_beta, const float* __restrict__ b_att_f,
    const float* __restrict__ b_att_h, const float* __restrict__ ann,
    ushort* __restrict__ Wg, ushort* __restrict__ Wcat2_bf,
    ushort* __restrict__ Wo_bf, ushort* __restrict__ Waf_bf,
    ushort* __restrict__ Whg_bf, ushort* __restrict__ ann_bf,
    float* __restrict__ biascR, float* __restrict__ b_hf)
{
  int idx = blockIdx.x * 256 + threadIdx.x;
  int stride = gridDim.x * 256;
  for (int i = idx; i < 12845056 / 8; i += stride)
    cvt8(ann + (size_t)i * 8, ann_bf + (size_t)i * 8);
  for (int i = idx; i < 3145728 / 8; i += stride) {
    int k8 = i * 8, rp = k8 / 1536, c = k8 - rp * 1536;
    int f = rp >> 2, g = rp & 3;
    int r = g * 512 + f;
    const float* src = (c < 1024) ? (W_ih + (size_t)r * 1024 + c)
                                  : (W_hh + (size_t)r * 512 + c - 1024);
    cvt8(src, Wg + k8);
  }
  for (int i = idx; i < 786432 / 8; i += stride) {
    int k8 = i * 8, r = k8 / 1536, c = k8 - r * 1536;
    const float* src = (c < 512) ? (W_y + (size_t)r * 512 + c)
                     : (c < 1024 ? (W_z + (size_t)r * 512 + c - 512)
                                 : (W_h + (size_t)r * 512 + c - 1024));
    cvt8(src, Wcat2_bf + k8);
  }
  for (int i = idx; i < 5177344 / 8; i += stride) {   // Wo: 10112x512, pad 0
    int r = i >> 6, c8 = i & 63;
    if (r < 10000) cvt8(W_out + (size_t)r * 512 + c8 * 8, Wo_bf + (size_t)i * 8);
    else { *(uint4*)(Wo_bf + (size_t)i * 8) = make_uint4(0, 0, 0, 0); }
  }
  for (int i = idx; i < 262144 / 8; i += stride)
    cvt8(W_att_f + i * 8, Waf_bf + i * 8);
  for (int i = idx; i < 524288 / 8; i += stride) {    // Whg: 1024x512
    int r = i >> 6, c8 = i & 63;
    const float* src = (r < 512) ? (W_att_h + (size_t)r * 512 + c8 * 8)
                                 : (W_beta + (size_t)(r - 512) * 512 + c8 * 8);
    cvt8(src, Whg_bf + (size_t)i * 8);
  }
  for (int i = idx; i < 2048; i += stride) {
    int f = i >> 2, g = i & 3;
    biascR[i] = b_ih[g * 512 + f] + b_hh[g * 512 + f];
  }
  for (int i = idx; i < 512; i += stride) b_hf[i] = b_att_h[i] + b_att_f[i];
}

// mean over L, dec_len; also resets the grid-barrier state for this replay.
__global__ __launch_bounds__(256) void k_mean(
    const float* __restrict__ ann, const int* __restrict__ lengths,
    float* __restrict__ meanb, int* __restrict__ declen,
    float* __restrict__ out_dec, unsigned* bar)
{
  int b = blockIdx.x, tid = threadIdx.x;
  const float* ab = ann + (size_t)b * 196 * 512;
  for (int f = tid; f < 512; f += 256) {
    float s = 0.f;
    for (int l = 0; l < 196; ++l) s += ab[l * 512 + f];
    meanb[b * 512 + f] = s * (1.f / 196.f);
  }
  if (tid == 0) {
    int d = lengths[b] - 1;
    if (d < 1) d = 1;
    declen[b] = d;
    out_dec[b] = (float)d;
    if (b == 0) { bar[0] = 0u; bar[64] = 0u; }
  }
}

// fp32 32x64-tile GEMM for h0/c0 init (tiny).
DEV float actf(float v, int act) { return act == 2 ? tanhf(v) : v; }
__global__ __launch_bounds__(256) void gemm32_k(
    const float* __restrict__ A, int lda, const float* __restrict__ W, int ldw,
    const float* __restrict__ bias, float* __restrict__ C, int ldc, int K, int act)
{
  __shared__ float As[32 * 36];
  __shared__ float Ws[32 * 68];
  const int tid = threadIdx.x;
  const int m0 = blockIdx.y * 32, n0 = blockIdx.x * 64;
  const int tx = tid & 15, ty = tid >> 4;
  const int r0 = ty * 2, c0 = tx * 4;
  const int lr = tid >> 3, lk = (tid & 7) * 4;
  const float* Ap = A + (size_t)(m0 + lr) * lda + lk;
  const float* Wp0 = W + (size_t)(n0 + lr) * ldw + lk;
  const float* Wp1 = W + (size_t)(n0 + lr + 32) * ldw + lk;
  float acc[2][4] = {{0.f, 0.f, 0.f, 0.f}, {0.f, 0.f, 0.f, 0.f}};
  for (int k0 = 0; k0 < K; k0 += 32) {
    float4 av = *(const float4*)(Ap + k0);
    float4 w0 = *(const float4*)(Wp0 + k0);
    float4 w1 = *(const float4*)(Wp1 + k0);
    __syncthreads();
    As[(lk + 0) * 36 + lr] = av.x; As[(lk + 1) * 36 + lr] = av.y;
    As[(lk + 2) * 36 + lr] = av.z; As[(lk + 3) * 36 + lr] = av.w;
    Ws[(lk + 0) * 68 + lr] = w0.x; Ws[(lk + 1) * 68 + lr] = w0.y;
    Ws[(lk + 2) * 68 + lr] = w0.z; Ws[(lk + 3) * 68 + lr] = w0.w;
    Ws[(lk + 0) * 68 + lr + 32] = w1.x; Ws[(lk + 1) * 68 + lr + 32] = w1.y;
    Ws[(lk + 2) * 68 + lr + 32] = w1.z; Ws[(lk + 3) * 68 + lr + 32] = w1.w;
    __syncthreads();
#pragma unroll
    for (int kk = 0; kk < 32; ++kk) {
      float2 a = *(const float2*)&As[kk * 36 + r0];
      float4 w = *(const float4*)&Ws[kk * 68 + c0];
      const float aa[2] = {a.x, a.y};
      const float* wwp = (const float*)&w;
#pragma unroll
      for (int i = 0; i < 2; ++i)
#pragma unroll
        for (int j = 0; j < 4; ++j)
          acc[i][j] = fmaf(aa[i], wwp[j], acc[i][j]);
    }
  }
#pragma unroll
  for (int i = 0; i < 2; ++i)
#pragma unroll
    for (int j = 0; j < 4; ++j)
      C[(size_t)(m0 + r0 + i) * ldc + n0 + c0 + j] =
          actf(acc[i][j] + bias[n0 + c0 + j], act);
}

__global__ __launch_bounds__(256) void k_cvt_h0(
    const float* __restrict__ h0f, ushort* __restrict__ x_cur)
{
  int idx = blockIdx.x * 256 + threadIdx.x;   // 65536
  int b = idx >> 9, j = idx & 511;
  x_cur[b * 1536 + 1024 + j] = f2bf(h0f[idx]);
}

// ---------------------------------------------------------------------------
extern "C" void kernel_launch(void* const* d_in, const int* in_sizes, int n_in,
                              void* d_out, int out_size, void* d_ws, size_t ws_size,
                              hipStream_t stream)
{
  const float* ann      = (const float*)d_in[0];
  const int*   captions = (const int*)d_in[1];
  const int*   lengths  = (const int*)d_in[2];
  const float* E_emb    = (const float*)d_in[3];
  const float* W_init_h = (const float*)d_in[4];
  const float* b_init_h = (const float*)d_in[5];
  const float* W_init_c = (const float*)d_in[6];
  const float* b_init_c = (const float*)d_in[7];
  const float* W_att_f  = (const float*)d_in[8];
  const float* b_att_f  = (const float*)d_in[9];
  const float* W_att_h  = (const float*)d_in[10];
  const float* b_att_h  = (const float*)d_in[11];
  const float* w_att_v  = (const float*)d_in[12];
  const float* b_att_v  = (const float*)d_in[13];
  const float* W_beta   = (const float*)d_in[14];
  const float* b_beta   = (const float*)d_in[15];
  const float* W_ih     = (const float*)d_in[16];
  const float* W_hh     = (const float*)d_in[17];
  const float* b_ih     = (const float*)d_in[18];
  const float* b_hh     = (const float*)d_in[19];
  const float* W_y      = (const float*)d_in[20];
  const float* W_h      = (const float*)d_in[21];
  const float* W_z      = (const float*)d_in[22];
  const float* W_out    = (const float*)d_in[23];
  const float* b_out    = (const float*)d_in[24];

  float* out        = (float*)d_out;
  float* out_logits = out;
  float* out_alpha  = out + 39680000ll;
  float* out_dec    = out + 40457728ll;

  char* p = (char*)d_ws;
  auto alloc_us = [&](size_t n) { ushort* r = (ushort*)p; p += ((n * 2 + 255) & ~(size_t)255); return r; };
  auto alloc_f  = [&](size_t n) { float*  r = (float*)p;  p += ((n * 4 + 255) & ~(size_t)255); return r; };
  ushort* Wo_bf    = alloc_us(10112 * 512);
  ushort* Wg_bf    = alloc_us(2048 * 1536);
  ushort* Wcat2_bf = alloc_us(512 * 1536);
  ushort* Waf_bf   = alloc_us(512 * 512);
  ushort* Whg_bf   = alloc_us(1024 * 512);
  ushort* ann_bf   = alloc_us(12845056);
  ushort* annp_bf  = alloc_us(12845056);
  ushort* preA_bf  = alloc_us(3968 * 512);
  ushort* x_cur    = alloc_us(128 * 1536);
  float* biascR = alloc_f(2048);
  float* b_hf   = alloc_f(512);
  float* hgP    = alloc_f(4 * 131072);
  float* preP   = alloc_f(8 * 65536);
  float* gP     = alloc_f(8 * 262144);
  float* cbuf   = alloc_f(65536);
  float* meanb  = alloc_f(65536);
  float* h0f    = alloc_f(65536);
  int*   declen = (int*)alloc_f(128);
  unsigned* bar = (unsigned*)alloc_f(128);

  // ---- phase 1 ----
  hipLaunchKernelGGL(k_prep, dim3(1024), dim3(256), 0, stream,
                     W_ih, W_hh, b_ih, b_hh, W_y, W_h, W_z, W_out,
                     W_att_f, W_att_h, W_beta, b_att_f, b_att_h, ann,
                     Wg_bf, Wcat2_bf, Wo_bf, Waf_bf, Whg_bf, ann_bf,
                     biascR, b_hf);
  hipLaunchKernelGGL(k_mean, dim3(128), dim3(256), 0, stream,
                     ann, lengths, meanb, declen, out_dec, bar);
  hipLaunchKernelGGL(gemm32_k, dim3(8, 4), dim3(256), 0, stream,
                     meanb, 512, W_init_h, 512, b_init_h, h0f, 512, 512, 2);
  hipLaunchKernelGGL(gemm32_k, dim3(8, 4), dim3(256), 0, stream,
                     meanb, 512, W_init_c, 512, b_init_c, cbuf, 512, 512, 2);
  hipLaunchKernelGGL(k_cvt_h0, dim3(256), dim3(256), 0, stream, h0f, x_cur);
  hipLaunchKernelGGL(k_mfma, dim3(4, 196), dim3(256), 0, stream,
                     ann_bf, 512, Waf_bf, 512, 512, 1, (const float*)nullptr,
                     (float*)nullptr, annp_bf, 512, 512, (const int*)nullptr);
  // init hp/gp from h0
  hipLaunchKernelGGL(k_tailhg, dim3(32), dim3(256), 0, stream,
                     x_cur, Whg_bf, hgP);

  // ---- phase 2: 31 steps in one persistent kernel (software grid barrier) --
  hipLaunchKernelGGL(k_steps, dim3(128), dim3(256), 0, stream,
                     annp_bf, ann_bf, hgP, preP, b_hf, b_beta, w_att_v,
                     b_att_v, captions, E_emb, declen, x_cur, preA_bf,
                     out_alpha, Wg_bf, gP, biascR, cbuf, Whg_bf, Wcat2_bf, bar);

  // ---- phase 3: logits ----
  hipLaunchKernelGGL(k_logits, dim3(2480), dim3(256), 0, stream,
                     preA_bf, Wo_bf, b_out, out_logits, declen);
}